// Round 1
// 162.363 us; speedup vs baseline: 1.1990x; 1.1990x over previous
//
#include <hip/hip_runtime.h>
#include <math.h>

#define NN 20000      // nodes
#define NE 320000     // edges (without self loops)
#define NT 340000     // edges + self loops
#define NG 64         // graphs
#define HB 1329       // ceil(NT/256) fused hist+scatter blocks
#define CB 128        // W2->bf16 transpose blocks
#define AB 2          // a2p GEMV blocks
#define SB 32         // sums-zero blocks (32*256 float4 = 32768 floats)

using short8  = __attribute__((ext_vector_type(8))) short;   // 8 x bf16 (4 VGPRs)
using float4v = __attribute__((ext_vector_type(4))) float;   // MFMA accumulator

__device__ __forceinline__ float lrelu(float v) { return v > 0.f ? v : 0.2f * v; }
__device__ __forceinline__ float elu1(float v)  { return v > 0.f ? v : (expf(v) - 1.f); }
__device__ __forceinline__ float bflo(unsigned u) { return __uint_as_float(u << 16); }
__device__ __forceinline__ float bfhi(unsigned u) { return __uint_as_float(u & 0xFFFF0000u); }
__device__ __forceinline__ unsigned short f2bf(float f) {
    unsigned u = __float_as_uint(f);
    u += 0x7FFFu + ((u >> 16) & 1u);   // round to nearest even
    return (unsigned short)(u >> 16);
}

#define ACC8(ex, hv) \
    acc[0] = fmaf(ex, bflo(hv.x), acc[0]); \
    acc[1] = fmaf(ex, bfhi(hv.x), acc[1]); \
    acc[2] = fmaf(ex, bflo(hv.y), acc[2]); \
    acc[3] = fmaf(ex, bfhi(hv.y), acc[3]); \
    acc[4] = fmaf(ex, bflo(hv.z), acc[4]); \
    acc[5] = fmaf(ex, bfhi(hv.z), acc[5]); \
    acc[6] = fmaf(ex, bflo(hv.w), acc[6]); \
    acc[7] = fmaf(ex, bfhi(hv.w), acc[7]);

// ---------- D1: fused prep ----------
// blocks [0,HB): hist+scatter in ONE pass — rank comes from the degree atomic, CSR has a
//                fixed stride of 64 slots/node (max real degree ~45 << 64, clamped).
// blocks [HB,HB+CB): W2 -> bf16 transpose.   [+AB): a2p GEMVs.   [+SB): zero `sums`.
// [+1): gstart binary searches.   rest: x@W1 + layer-1 attention logits.
__global__ void k_prep(const int* __restrict__ ei, int* __restrict__ deg,
                       int* __restrict__ csr64,
                       const float* __restrict__ W2, unsigned short* __restrict__ W2bfT,
                       const float* __restrict__ as2, const float* __restrict__ ad2,
                       float* __restrict__ a2ps, float* __restrict__ a2pd,
                       const float* __restrict__ x, const float* __restrict__ W1,
                       const float* __restrict__ as1, const float* __restrict__ ad1,
                       unsigned short* __restrict__ h1bf, float* __restrict__ al_s,
                       float* __restrict__ al_d,
                       const int* __restrict__ batch, int* __restrict__ gstart,
                       float* __restrict__ sums) {
    int tid = threadIdx.x;
    int b = blockIdx.x;
    if (b < HB) {
        int t = b * 256 + tid;
        if (t < NT) {
            int s, d;
            if (t < NE) { s = ei[t]; d = ei[NE + t]; }
            else        { s = d = t - NE; }            // self loop
            int r = atomicAdd(&deg[d], 1);             // rank within dst row
            if (r < 64) csr64[(d << 6) + r] = s;
        }
        return;
    }
    if (b < HB + CB) {
        int t = (b - HB) * 256 + tid;  // t = n*64 + k
        int k = t & 63, n = t >> 6;
        W2bfT[t] = f2bf(W2[k * 512 + n]);
        return;
    }
    if (b < HB + CB + AB) {
        // a2p[k] = sum_j W2[k][j] * a[j]   (64x512 GEMV)
        __shared__ float pp[4][64];
        const float* av = (b == HB + CB) ? as2 : ad2;
        float* outp     = (b == HB + CB) ? a2ps : a2pd;
        int k = tid & 63, seg = tid >> 6;
        float s = 0.f;
        for (int j = seg * 128; j < seg * 128 + 128; ++j)
            s = fmaf(W2[k * 512 + j], av[j], s);
        pp[seg][k] = s;
        __syncthreads();
        if (tid < 64) outp[tid] = pp[0][tid] + pp[1][tid] + pp[2][tid] + pp[3][tid];
        return;
    }
    if (b < HB + CB + AB + SB) {
        int t = (b - HB - CB - AB) * 256 + tid;
        float4 zz = {0.f, 0.f, 0.f, 0.f};
        ((float4*)sums)[t] = zz;       // 32 blocks * 256 * 4 floats = 32768
        return;
    }
    if (b == HB + CB + AB + SB) {
        if (tid <= NG) {               // per-graph node-range starts (batch is sorted)
            int lo = 0, hi = NN;
            while (lo < hi) {
                int mid = (lo + hi) >> 1;
                if (batch[mid] < tid) lo = mid + 1; else hi = mid;
            }
            gstart[tid] = lo;
        }
        return;
    }
    int n = (b - HB - CB - AB - SB - 1) * 4 + (tid >> 6);
    int j = tid & 63;
    float x0 = x[n * 3 + 0], x1 = x[n * 3 + 1], x2 = x[n * 3 + 2];
    float v = fmaf(x0, W1[j], fmaf(x1, W1[64 + j], x2 * W1[128 + j]));
    h1bf[n * 64 + j] = f2bf(v);
    float ps = v * as1[j];
    float pd = v * ad1[j];
    for (int o = 4; o >= 1; o >>= 1) {
        ps += __shfl_xor(ps, o, 8);
        pd += __shfl_xor(pd, o, 8);
    }
    if ((j & 7) == 0) {
        al_s[n * 8 + (j >> 3)] = ps;
        al_d[n * 8 + (j >> 3)] = pd;
    }
}

// ---------- D2: fused layer-1 softmax+aggregate + elu; layer-2 logits ----------
// 4 nodes/block (1 wave each). Octet layout: lane=(e8,c8); c8 = head. Whole adjacency row
// is loaded with ONE coalesced load (csr64[n*64+lane]); per-chunk src ids come from shfl
// (LDS speed) instead of a dependent L2 load.
__global__ void k_l1(const int* __restrict__ deg, const int* __restrict__ csr64,
                     const float* __restrict__ al_s, const float* __restrict__ al_d,
                     const unsigned short* __restrict__ h1bf, const float* __restrict__ b1,
                     const float* __restrict__ a2ps, const float* __restrict__ a2pd,
                     unsigned short* __restrict__ o1bf, float* __restrict__ al_s2,
                     float* __restrict__ al_d2) {
    int nb = threadIdx.x >> 6;
    int n = blockIdx.x * 4 + nb;
    int lane = threadIdx.x & 63;
    int e8 = lane >> 3, c8 = lane & 7;   // edge slot, head
    int dg = deg[n]; dg = dg < 64 ? dg : 64;
    int sAll = csr64[(n << 6) + (lane < dg ? lane : 0)];
    float ald = al_d[n * 8 + c8];
    float acc[8] = {0.f, 0.f, 0.f, 0.f, 0.f, 0.f, 0.f, 0.f};
    float dsum = 0.f;
    for (int base = 0; base < dg; base += 16) {
        int sA = __shfl(sAll, base + e8, 64);
        int sB = __shfl(sAll, base + 8 + e8, 64);
        float exA = 0.f, exB = 0.f;
        if (base + e8 < dg)     exA = __expf(lrelu(al_s[sA * 8 + c8] + ald));
        if (base + 8 + e8 < dg) exB = __expf(lrelu(al_s[sB * 8 + c8] + ald));
        dsum += exA + exB;
        uint4 hA = *(const uint4*)(h1bf + sA * 64 + c8 * 8);
        uint4 hB = *(const uint4*)(h1bf + sB * 64 + c8 * 8);
        ACC8(exA, hA);
        ACC8(exB, hB);
    }
    // reduce acc[8] + dsum across the 8 edge slots (lane bits 3..5)
#pragma unroll
    for (int o = 32; o >= 8; o >>= 1) {
#pragma unroll
        for (int k = 0; k < 8; ++k) acc[k] += __shfl_xor(acc[k], o, 64);
        dsum += __shfl_xor(dsum, o, 64);
    }
    if (e8 == 0) {   // lanes 0..7: finalize head c8's 8 channels
        float inv = 1.f / dsum;
        const float* bp = b1 + c8 * 8;
        float v[8];
#pragma unroll
        for (int k = 0; k < 8; ++k) v[k] = elu1(acc[k] * inv + bp[k]);
        uint4 pk;
        pk.x = (unsigned)f2bf(v[0]) | ((unsigned)f2bf(v[1]) << 16);
        pk.y = (unsigned)f2bf(v[2]) | ((unsigned)f2bf(v[3]) << 16);
        pk.z = (unsigned)f2bf(v[4]) | ((unsigned)f2bf(v[5]) << 16);
        pk.w = (unsigned)f2bf(v[6]) | ((unsigned)f2bf(v[7]) << 16);
        *(uint4*)(o1bf + n * 64 + c8 * 8) = pk;
        float ps = 0.f, pd = 0.f;
        const float* asp = a2ps + c8 * 8;
        const float* adp = a2pd + c8 * 8;
#pragma unroll
        for (int k = 0; k < 8; ++k) {
            ps = fmaf(v[k], asp[k], ps);
            pd = fmaf(v[k], adp[k], pd);
        }
        for (int o = 4; o >= 1; o >>= 1) {
            ps += __shfl_xor(ps, o, 8);
            pd += __shfl_xor(pd, o, 8);
        }
        if (c8 == 0) { al_s2[n] = ps; al_d2[n] = pd; }
    }
}

// ---------- D3: fused layer-2 softmax-agg + MFMA @W2 + elu + pool ----------
// 16 nodes/block, 512 threads (8 waves). Single head: every lane precomputes its OWN
// edge's ex once (one gather + exp); chunk loop only gathers h rows, ex comes via shfl.
__global__ void k_l2gemm(const int* __restrict__ deg, const int* __restrict__ csr64,
                         const float* __restrict__ al_s2, const float* __restrict__ al_d2,
                         const unsigned short* __restrict__ o1bf,
                         const unsigned short* __restrict__ W2bfT,
                         const float* __restrict__ b2, const int* __restrict__ batch,
                         float* __restrict__ sums) {
    __shared__ unsigned short lagg[16][72];   // padded rows: 144B stride
    int n0 = blockIdx.x * 16;
    int w = threadIdx.x >> 6, lane = threadIdx.x & 63;
    int e8 = lane >> 3, c8 = lane & 7;
#pragma unroll
    for (int i = 0; i < 2; ++i) {
        int r = w * 2 + i;
        int n = n0 + r;
        float ald = al_d2[n];
        int dg = deg[n]; dg = dg < 64 ? dg : 64;
        int sAll = csr64[(n << 6) + (lane < dg ? lane : 0)];
        float exAll = 0.f;
        if (lane < dg) exAll = __expf(lrelu(al_s2[sAll] + ald));
        // full-wave denominator: pre-reduce over lane bits 0..2, finish with bits 3..5 below
        float dsum = exAll;
        dsum += __shfl_xor(dsum, 1, 64);
        dsum += __shfl_xor(dsum, 2, 64);
        dsum += __shfl_xor(dsum, 4, 64);
        float acc[8] = {0.f, 0.f, 0.f, 0.f, 0.f, 0.f, 0.f, 0.f};
        for (int base = 0; base < dg; base += 16) {
            int sA   = __shfl(sAll, base + e8, 64);
            int sB   = __shfl(sAll, base + 8 + e8, 64);
            float exA = __shfl(exAll, base + e8, 64);      // 0 for invalid slots
            float exB = __shfl(exAll, base + 8 + e8, 64);
            uint4 hA = *(const uint4*)(o1bf + sA * 64 + c8 * 8);
            uint4 hB = *(const uint4*)(o1bf + sB * 64 + c8 * 8);
            ACC8(exA, hA);
            ACC8(exB, hB);
        }
#pragma unroll
        for (int o = 32; o >= 8; o >>= 1) {
#pragma unroll
            for (int k = 0; k < 8; ++k) acc[k] += __shfl_xor(acc[k], o, 64);
            dsum += __shfl_xor(dsum, o, 64);
        }
        if (e8 == 0) {   // lanes 0..7 pack channels c8*8..+7
            float inv = 1.f / dsum;
            uint4 pk;
            pk.x = (unsigned)f2bf(acc[0] * inv) | ((unsigned)f2bf(acc[1] * inv) << 16);
            pk.y = (unsigned)f2bf(acc[2] * inv) | ((unsigned)f2bf(acc[3] * inv) << 16);
            pk.z = (unsigned)f2bf(acc[4] * inv) | ((unsigned)f2bf(acc[5] * inv) << 16);
            pk.w = (unsigned)f2bf(acc[6] * inv) | ((unsigned)f2bf(acc[7] * inv) << 16);
            *(uint4*)&lagg[r][c8 * 8] = pk;
        }
    }
    __syncthreads();
    // phase B: A[m=lane&15][k=quad*8+j] from LDS; B[k][n=lane&15] from W2bfT (n-major).
    int mcol = lane & 15;
    int q = lane >> 4;
    short8 a0 = *(const short8*)&lagg[mcol][q * 8];
    short8 a1 = *(const short8*)&lagg[mcol][32 + q * 8];
    int gmin = batch[n0], gmax = batch[n0 + 15];
    int batchq[4];
#pragma unroll
    for (int r = 0; r < 4; ++r) batchq[r] = batch[n0 + q * 4 + r];
#pragma unroll
    for (int t = 0; t < 4; ++t) {
        int c = w * 64 + t * 16 + mcol;
        const unsigned short* bp = W2bfT + c * 64 + q * 8;
        short8 b0 = *(const short8*)bp;
        short8 b1v = *(const short8*)(bp + 32);
        float4v acc = {0.f, 0.f, 0.f, 0.f};
        acc = __builtin_amdgcn_mfma_f32_16x16x32_bf16(a0, b0, acc, 0, 0, 0);
        acc = __builtin_amdgcn_mfma_f32_16x16x32_bf16(a1, b1v, acc, 0, 0, 0);
        float bias = b2[c];
        float val[4];
#pragma unroll
        for (int r = 0; r < 4; ++r) val[r] = elu1(acc[r] + bias);
        for (int g = gmin; g <= gmax; ++g) {
            float s = 0.f;
#pragma unroll
            for (int r = 0; r < 4; ++r) s += (batchq[r] == g) ? val[r] : 0.f;
            s += __shfl_xor(s, 16, 64);   // reduce across the 4 quads
            s += __shfl_xor(s, 32, 64);
            if (q == 0) atomicAdd(&sums[g * 512 + c], s);
        }
    }
}

// ---------- D4: final GEMM: out[g][j] = (sums[g] @ Wo[:,j]) / cnt[g] + bo[j] ----------
__global__ void k_final(const float* __restrict__ sums, const int* __restrict__ gstart,
                        const float* __restrict__ Wo, const float* __restrict__ bo,
                        float* __restrict__ out) {
    __shared__ float sp[512];
    int g = blockIdx.x >> 3;
    int j = (blockIdx.x & 7) * 64 + threadIdx.x;  // 64 threads
    for (int k = threadIdx.x; k < 512; k += 64) sp[k] = sums[g * 512 + k];
    __syncthreads();
    float c = (float)(gstart[g + 1] - gstart[g]);
    float inv = 1.f / (c > 0.f ? c : 1.f);
    float acc = 0.f;
    for (int k = 0; k < 512; ++k) acc = fmaf(sp[k], Wo[k * 512 + j], acc);
    out[g * 512 + j] = fmaf(acc, inv, bo[j]);
}

extern "C" void kernel_launch(void* const* d_in, const int* in_sizes, int n_in,
                              void* d_out, int out_size, void* d_ws, size_t ws_size,
                              hipStream_t stream) {
    const float* x     = (const float*)d_in[0];
    const int*   ei    = (const int*)d_in[1];    // [2, NE] (int32: jax x64 disabled)
    const int*   batch = (const int*)d_in[2];    // [NN] sorted
    const float* W1    = (const float*)d_in[3];
    const float* as1   = (const float*)d_in[4];
    const float* ad1   = (const float*)d_in[5];
    const float* b1    = (const float*)d_in[6];
    const float* W2    = (const float*)d_in[7];
    const float* as2   = (const float*)d_in[8];
    const float* ad2   = (const float*)d_in[9];
    const float* b2    = (const float*)d_in[10];
    const float* Wo    = (const float*)d_in[11];
    const float* bo    = (const float*)d_in[12];
    float* out = (float*)d_out;

    // ---- workspace arena (4-byte units) ----
    float* w = (float*)d_ws;
    unsigned short* h1bf  = (unsigned short*)(w + 0);        // 640,000 units
    float* al_s1 = w + 640000;     // 160,000
    float* al_d1 = w + 800000;     // 160,000
    unsigned short* o1bf  = (unsigned short*)(w + 960000);   // 640,000 units (16B aligned)
    unsigned short* W2bfT = (unsigned short*)(w + 1600000);  // 16,384 units (16B aligned)
    float* a2ps  = w + 1616384;    // 64
    float* a2pd  = w + 1616448;    // 64
    float* al_s2 = w + 1616512;    // 20,000
    float* al_d2 = w + 1636512;    // 20,000
    int*   gstart = (int*)(w + 1656512);   // 65
    int*   csr64  = (int*)(w + 1656580);   // 1,280,000 (fixed-stride CSR, 64 slots/node)
    float* sums   = w + 2936580;           // 32,768 (16B aligned; zeroed in k_prep)
    // ---- zero-initialized region (single small memset) ----
    int*   deg    = (int*)(w + 2969348);   // 20,000
    // end: 2,989,348 units ≈ 12.0 MB

    hipMemsetAsync(deg, 0, (size_t)20000 * 4, stream);

    k_prep   <<<HB + CB + AB + SB + 1 + NN / 4, 256, 0, stream>>>(
        ei, deg, csr64, W2, W2bfT, as2, ad2, a2ps, a2pd,
        x, W1, as1, ad1, h1bf, al_s1, al_d1, batch, gstart, sums);
    k_l1     <<<NN / 4, 256, 0, stream>>>(deg, csr64, al_s1, al_d1, h1bf, b1,
                                          a2ps, a2pd, o1bf, al_s2, al_d2);
    k_l2gemm <<<NN / 16, 512, 0, stream>>>(deg, csr64, al_s2, al_d2, o1bf,
                                           W2bfT, b2, batch, sums);
    k_final  <<<NG * 8, 64, 0, stream>>>(sums, gstart, Wo, bo, out);
}